// Round 2
// baseline (368.044 us; speedup 1.0000x reference)
//
#include <hip/hip_runtime.h>
#include <hip/hip_bf16.h>
#include <math.h>

// Mixer2dTriU: B=64, T=512, C=512, fp32 in/out.
// Round 2: GEMMs restructured to barrier-free direct-from-global MFMA
// (register double-buffered fragments, no LDS staging) — the m97 2-barrier
// K-loop was latency-bound at K=512 (MfmaUtil 12.6%).

#define B_ 64
#define T_ 512
#define C_ 512
#define TC_ (T_ * C_)
static_assert(TC_ == 262144, "");

typedef __attribute__((ext_vector_type(8))) short bf16x8;
typedef __attribute__((ext_vector_type(4))) float f32x4;

__device__ __forceinline__ unsigned short f2bf(float f) {
  union { float f; unsigned u; } v; v.f = f;
  unsigned r = v.u + 0x7FFF + ((v.u >> 16) & 1);   // RNE
  return (unsigned short)(r >> 16);
}
__device__ __forceinline__ float bf2f(unsigned short h) {
  union { unsigned u; float f; } v; v.u = ((unsigned)h) << 16; return v.f;
}

// ---------------- weight conversion ----------------
__global__ __launch_bounds__(256) void conv_weights(
    const float* __restrict__ triM, const float* __restrict__ d1w,
    const float* __restrict__ d2w, unsigned short* __restrict__ Mb,
    unsigned short* __restrict__ W1b, unsigned short* __restrict__ W2b) {
  const int idx = blockIdx.x * 256 + threadIdx.x;   // 262144 total
  const int i = idx >> 9, j = idx & 511;
  Mb[idx]  = (j <= i) ? f2bf(triM[idx]) : (unsigned short)0;
  W1b[idx] = f2bf(d1w[idx]);
  W2b[idx] = f2bf(d2w[idx]);
}

// ---------------- ln1 stats: per-batch sum / sumsq ----------------
__global__ __launch_bounds__(256) void ln_stats(const float* __restrict__ x,
                                                float* __restrict__ red) {
  const int b = blockIdx.x;
  const int s = blockIdx.y;                       // 16 splits
  const float4* p = (const float4*)(x + (size_t)b * TC_) + (size_t)s * 4096;
  float s1 = 0.f, s2 = 0.f;
  for (int i = threadIdx.x; i < 4096; i += 256) {
    float4 v = p[i];
    s1 += v.x + v.y + v.z + v.w;
    s2 += v.x * v.x + v.y * v.y + v.z * v.z + v.w * v.w;
  }
#pragma unroll
  for (int o = 32; o; o >>= 1) { s1 += __shfl_down(s1, o, 64); s2 += __shfl_down(s2, o, 64); }
  __shared__ float sm[8];
  const int w = threadIdx.x >> 6, lane = threadIdx.x & 63;
  if (lane == 0) { sm[w * 2] = s1; sm[w * 2 + 1] = s2; }
  __syncthreads();
  if (threadIdx.x == 0) {
    float a = 0.f, c = 0.f;
    for (int i = 0; i < 4; ++i) { a += sm[2 * i]; c += sm[2 * i + 1]; }
    atomicAdd(&red[b * 2], a);
    atomicAdd(&red[b * 2 + 1], c);
  }
}

// ------------- ln1 normalize + transposed bf16 write -------------
// writes XnT[b][c][t] so the mixer GEMM's B-operand is contiguous along K(=t)
__global__ __launch_bounds__(256) void ln1_norm_t(
    const float* __restrict__ x, const float* __restrict__ w,
    const float* __restrict__ bvec, const float* __restrict__ red1,
    unsigned short* __restrict__ XnT) {
  __shared__ unsigned short tile[64][65];
  const int b = blockIdx.z;
  const int t0 = blockIdx.y * 64;
  const int c0 = blockIdx.x * 64;
  const float mu = red1[b * 2] * (1.f / TC_);
  const float rstd = rsqrtf(red1[b * 2 + 1] * (1.f / TC_) - mu * mu + 1e-5f);
  const int tid = threadIdx.x;
  const int r = tid >> 4;            // 0..15
  const int cg = (tid & 15) * 4;     // 0..60
#pragma unroll
  for (int rr = 0; rr < 4; ++rr) {
    const int t = t0 + rr * 16 + r;
    const float4 xv = *(const float4*)&x[((size_t)b * T_ + t) * C_ + c0 + cg];
    const float4 wv = *(const float4*)&w[(size_t)t * C_ + c0 + cg];
    const float4 bv = *(const float4*)&bvec[(size_t)t * C_ + c0 + cg];
    tile[rr * 16 + r][cg + 0] = f2bf((xv.x - mu) * rstd * wv.x + bv.x);
    tile[rr * 16 + r][cg + 1] = f2bf((xv.y - mu) * rstd * wv.y + bv.y);
    tile[rr * 16 + r][cg + 2] = f2bf((xv.z - mu) * rstd * wv.z + bv.z);
    tile[rr * 16 + r][cg + 3] = f2bf((xv.w - mu) * rstd * wv.w + bv.w);
  }
  __syncthreads();
  const int cl = tid >> 2;           // 0..63
  const int tg = (tid & 3) * 16;     // 0,16,32,48
  alignas(16) unsigned short tmp[16];
#pragma unroll
  for (int j = 0; j < 16; ++j) tmp[j] = tile[tg + j][cl];
  unsigned short* o = &XnT[((size_t)b * C_ + c0 + cl) * T_ + t0 + tg];
  *(uint4*)&o[0] = *(const uint4*)&tmp[0];
  *(uint4*)&o[8] = *(const uint4*)&tmp[8];
}

// ---------------- direct-from-global GEMM mainloop ----------------
// C[128x128] = A[128xK] @ BT[128xK]^T, A/BT row-major bf16, fp32 acc.
// No LDS, no barriers: each wave loads its MFMA fragments straight from
// global (16 B/lane, coalesced in 64 B row-chunks), register double-buffer.
__device__ __forceinline__ void gemm_direct(
    const unsigned short* __restrict__ Ag,   // at row i0, ld = lda
    const unsigned short* __restrict__ Bg,   // at row n0 (of BT), ld = ldb
    int lda, int ldb, int ktiles, f32x4 acc[4][4], int tid) {
  const int lane = tid & 63;
  const int w = tid >> 6;
  const int wr = (w >> 1) * 64;
  const int wc = (w & 1) * 64;
  const int m16 = lane & 15;
  const int quad = lane >> 4;
  const unsigned short* ap[4];
  const unsigned short* bp[4];
#pragma unroll
  for (int r = 0; r < 4; ++r)
    ap[r] = Ag + (size_t)(wr + r * 16 + m16) * lda + quad * 8;
#pragma unroll
  for (int c = 0; c < 4; ++c)
    bp[c] = Bg + (size_t)(wc + c * 16 + m16) * ldb + quad * 8;
  bf16x8 a0[4], b0[4], a1[4], b1[4];
#pragma unroll
  for (int r = 0; r < 4; ++r) a0[r] = *(const bf16x8*)(ap[r]);
#pragma unroll
  for (int c = 0; c < 4; ++c) b0[c] = *(const bf16x8*)(bp[c]);
  for (int kt = 0; kt < ktiles - 1; ++kt) {
    const int ko = (kt + 1) * 32;
#pragma unroll
    for (int r = 0; r < 4; ++r) a1[r] = *(const bf16x8*)(ap[r] + ko);
#pragma unroll
    for (int c = 0; c < 4; ++c) b1[c] = *(const bf16x8*)(bp[c] + ko);
#pragma unroll
    for (int r = 0; r < 4; ++r)
#pragma unroll
      for (int c = 0; c < 4; ++c)
        acc[r][c] = __builtin_amdgcn_mfma_f32_16x16x32_bf16(a0[r], b0[c], acc[r][c], 0, 0, 0);
#pragma unroll
    for (int r = 0; r < 4; ++r) a0[r] = a1[r];
#pragma unroll
    for (int c = 0; c < 4; ++c) b0[c] = b1[c];
  }
#pragma unroll
  for (int r = 0; r < 4; ++r)
#pragma unroll
    for (int c = 0; c < 4; ++c)
      acc[r][c] = __builtin_amdgcn_mfma_f32_16x16x32_bf16(a0[r], b0[c], acc[r][c], 0, 0, 0);
}

// ---------------- mixer GEMM: Z = tril(M)@Xn + tri_b + inputs ----------------
__global__ __launch_bounds__(256) void gemm_mixer(
    const unsigned short* __restrict__ Mb, const unsigned short* __restrict__ XnT,
    const float* __restrict__ trib, const float* __restrict__ inp,
    unsigned short* __restrict__ Z, float* __restrict__ red2) {
  const int b = blockIdx.z;
  const int i0 = blockIdx.y * 128;
  const int c0 = blockIdx.x * 128;
  f32x4 acc[4][4];
#pragma unroll
  for (int r = 0; r < 4; ++r)
#pragma unroll
    for (int c = 0; c < 4; ++c) acc[r][c] = (f32x4){0.f, 0.f, 0.f, 0.f};
  // tril: rows < i0+128 only need k < i0+128
  gemm_direct(Mb + (size_t)i0 * T_, XnT + (size_t)b * TC_ + (size_t)c0 * T_,
              T_, T_, (i0 >> 5) + 4, acc, threadIdx.x);
  const int tid = threadIdx.x, lane = tid & 63, w = tid >> 6;
  const int wr = (w >> 1) * 64, wc = (w & 1) * 64, m16 = lane & 15, quad = lane >> 4;
  float s1 = 0.f, s2 = 0.f;
#pragma unroll
  for (int r = 0; r < 4; ++r) {
#pragma unroll
    for (int g = 0; g < 4; ++g) {
      const int i = i0 + wr + r * 16 + quad * 4 + g;
      const float tb = trib[i];
      const float* inrow = &inp[((size_t)b * T_ + i) * C_];
      unsigned short* zrow = &Z[((size_t)b * T_ + i) * C_];
#pragma unroll
      for (int c = 0; c < 4; ++c) {
        const int ch = c0 + wc + c * 16 + m16;
        const float v = acc[r][c][g] + tb + inrow[ch];
        zrow[ch] = f2bf(v);
        s1 += v; s2 += v * v;
      }
    }
  }
#pragma unroll
  for (int o = 32; o; o >>= 1) { s1 += __shfl_down(s1, o, 64); s2 += __shfl_down(s2, o, 64); }
  __shared__ float sm[8];
  if (lane == 0) { sm[w * 2] = s1; sm[w * 2 + 1] = s2; }
  __syncthreads();
  if (tid == 0) {
    float a = 0.f, c2 = 0.f;
    for (int i = 0; i < 4; ++i) { a += sm[2 * i]; c2 += sm[2 * i + 1]; }
    atomicAdd(&red2[b * 2], a);
    atomicAdd(&red2[b * 2 + 1], c2);
  }
}

// ---------------- ln2 normalize ----------------
__global__ __launch_bounds__(256) void ln2_norm(
    const unsigned short* __restrict__ Z, const float* __restrict__ red2,
    const float* __restrict__ w, const float* __restrict__ bvec,
    unsigned short* __restrict__ X2) {
  const size_t e = ((size_t)blockIdx.x * 256 + threadIdx.x) * 8;
  const int b = (int)(e >> 18);
  const int tc = (int)(e & (TC_ - 1));
  const float mu = red2[b * 2] * (1.f / TC_);
  const float rstd = rsqrtf(red2[b * 2 + 1] * (1.f / TC_) - mu * mu + 1e-5f);
  uint4 zp = *(const uint4*)&Z[e];
  const unsigned short* zs = (const unsigned short*)&zp;
  alignas(16) float wv[8], bb[8];
  *(float4*)&wv[0] = *(const float4*)&w[tc];
  *(float4*)&wv[4] = *(const float4*)&w[tc + 4];
  *(float4*)&bb[0] = *(const float4*)&bvec[tc];
  *(float4*)&bb[4] = *(const float4*)&bvec[tc + 4];
  alignas(16) unsigned short o[8];
#pragma unroll
  for (int j = 0; j < 8; ++j)
    o[j] = f2bf((bf2f(zs[j]) - mu) * rstd * wv[j] + bb[j]);
  *(uint4*)&X2[e] = *(const uint4*)&o[0];
}

// ---------------- MLP GEMM 1: H = gelu(X2 @ W1^T + b1) ----------------
__global__ __launch_bounds__(256) void gemm_d1(
    const unsigned short* __restrict__ X2, const unsigned short* __restrict__ W1b,
    const float* __restrict__ d1b, unsigned short* __restrict__ H) {
  const int i0 = blockIdx.y * 128;
  const int n0 = blockIdx.x * 128;
  f32x4 acc[4][4];
#pragma unroll
  for (int r = 0; r < 4; ++r)
#pragma unroll
    for (int c = 0; c < 4; ++c) acc[r][c] = (f32x4){0.f, 0.f, 0.f, 0.f};
  gemm_direct(X2 + (size_t)i0 * C_, W1b + (size_t)n0 * C_, C_, C_, 16,
              acc, threadIdx.x);
  const int tid = threadIdx.x, lane = tid & 63, w = tid >> 6;
  const int wr = (w >> 1) * 64, wc = (w & 1) * 64, m16 = lane & 15, quad = lane >> 4;
#pragma unroll
  for (int r = 0; r < 4; ++r) {
#pragma unroll
    for (int g = 0; g < 4; ++g) {
      const int row = i0 + wr + r * 16 + quad * 4 + g;
#pragma unroll
      for (int c = 0; c < 4; ++c) {
        const int n = n0 + wc + c * 16 + m16;
        const float v = acc[r][c][g] + d1b[n];
        const float gl = 0.5f * v * (1.0f + erff(v * 0.70710678118654752f));
        H[(size_t)row * C_ + n] = f2bf(gl);
      }
    }
  }
}

// ---------------- MLP GEMM 2: out = X2 + H @ W2^T + b2 ----------------
__global__ __launch_bounds__(256) void gemm_d2(
    const unsigned short* __restrict__ H, const unsigned short* __restrict__ W2b,
    const float* __restrict__ d2b, const unsigned short* __restrict__ X2,
    float* __restrict__ out) {
  const int i0 = blockIdx.y * 128;
  const int n0 = blockIdx.x * 128;
  f32x4 acc[4][4];
#pragma unroll
  for (int r = 0; r < 4; ++r)
#pragma unroll
    for (int c = 0; c < 4; ++c) acc[r][c] = (f32x4){0.f, 0.f, 0.f, 0.f};
  gemm_direct(H + (size_t)i0 * C_, W2b + (size_t)n0 * C_, C_, C_, 16,
              acc, threadIdx.x);
  const int tid = threadIdx.x, lane = tid & 63, w = tid >> 6;
  const int wr = (w >> 1) * 64, wc = (w & 1) * 64, m16 = lane & 15, quad = lane >> 4;
#pragma unroll
  for (int r = 0; r < 4; ++r) {
#pragma unroll
    for (int g = 0; g < 4; ++g) {
      const int row = i0 + wr + r * 16 + quad * 4 + g;
#pragma unroll
      for (int c = 0; c < 4; ++c) {
        const int n = n0 + wc + c * 16 + m16;
        out[(size_t)row * C_ + n] = acc[r][c][g] + d2b[n] + bf2f(X2[(size_t)row * C_ + n]);
      }
    }
  }
}

extern "C" void kernel_launch(void* const* d_in, const int* in_sizes, int n_in,
                              void* d_out, int out_size, void* d_ws, size_t ws_size,
                              hipStream_t stream) {
  const float* inp  = (const float*)d_in[0];
  const float* ln1w = (const float*)d_in[1];
  const float* ln1b = (const float*)d_in[2];
  const float* ln2w = (const float*)d_in[3];
  const float* ln2b = (const float*)d_in[4];
  const float* triM = (const float*)d_in[5];
  const float* trib = (const float*)d_in[6];
  const float* d1w  = (const float*)d_in[7];
  const float* d1b  = (const float*)d_in[8];
  const float* d2w  = (const float*)d_in[9];
  const float* d2b  = (const float*)d_in[10];
  float* out = (float*)d_out;

  char* ws = (char*)d_ws;
  float* red1 = (float*)ws;                         // 64*2 floats
  float* red2 = (float*)(ws + 512);                 // 64*2 floats
  unsigned short* Mb  = (unsigned short*)(ws + 1024);
  unsigned short* W1b = Mb + TC_;
  unsigned short* W2b = W1b + TC_;
  unsigned short* XnT = W2b + TC_;                  // [B][C][T] bf16
  unsigned short* Z   = XnT + (size_t)B_ * TC_;     // [B][T][C] bf16
  unsigned short* X2  = Z + (size_t)B_ * TC_;       // [B][T][C] bf16
  unsigned short* H   = X2 + (size_t)B_ * TC_;      // [B*T][C] bf16

  hipMemsetAsync(ws, 0, 1024, stream);
  conv_weights<<<1024, 256, 0, stream>>>(triM, d1w, d2w, Mb, W1b, W2b);
  ln_stats<<<dim3(B_, 16), 256, 0, stream>>>(inp, red1);
  ln1_norm_t<<<dim3(8, 8, B_), 256, 0, stream>>>(inp, ln1w, ln1b, red1, XnT);
  gemm_mixer<<<dim3(4, 4, B_), 256, 0, stream>>>(Mb, XnT, trib, inp, Z, red2);
  ln2_norm<<<8192, 256, 0, stream>>>(Z, red2, ln2w, ln2b, X2);
  gemm_d1<<<dim3(4, 256), 256, 0, stream>>>(X2, W1b, d1b, H);
  gemm_d2<<<dim3(4, 256), 256, 0, stream>>>(H, W2b, d2b, X2, out);
}

// Round 3
// 282.742 us; speedup vs baseline: 1.3017x; 1.3017x over previous
//
#include <hip/hip_runtime.h>
#include <hip/hip_bf16.h>
#include <math.h>

// Mixer2dTriU: B=64, T=512, C=512, fp32 in/out.
// Round 3: all GEMM operands pre-packed into MFMA-fragment-major layout so
// every fragment load is ONE contiguous 1KB wave load (global_load_dwordx4,
// lane*16B). Barrier-free direct-from-global GEMMs with 2-stage ping-pong.
//
// Packed layout for a [R x 512] bf16 matrix (k = 512, KT = 16 k-tiles):
//   element (row, k) -> chunk = ((row>>4)*16 + (k>>5))*64 + ((k>>3)&3)*16 + (row&15)
//   stored at  ptr[chunk*8 + (k&7)]    (16B per chunk, lane-major)
// A wave's MFMA fragment (lane = quad*16+m16 holds (row = r*16+m16, k = kt*32+quad*8+j))
// is exactly chunk range [ (r*16+kt)*64 , +64 ) -> base + lane*16B.

#define B_ 64
#define T_ 512
#define C_ 512
#define TC_ (T_ * C_)
static_assert(TC_ == 262144, "");

typedef __attribute__((ext_vector_type(8))) short bf16x8;
typedef __attribute__((ext_vector_type(4))) float f32x4;

__device__ __forceinline__ unsigned short f2bf(float f) {
  union { float f; unsigned u; } v; v.f = f;
  unsigned r = v.u + 0x7FFF + ((v.u >> 16) & 1);   // RNE
  return (unsigned short)(r >> 16);
}
__device__ __forceinline__ float bf2f(unsigned short h) {
  union { unsigned u; float f; } v; v.u = ((unsigned)h) << 16; return v.f;
}

// packed chunk index for element (row, k) of a K=512 matrix
__device__ __forceinline__ size_t pidx(int row, int k) {
  return ((size_t)((row >> 4) * 16 + (k >> 5)) * 64 + ((k >> 3) & 3) * 16 + (row & 15)) * 8 + (k & 7);
}

// ---------------- weight conversion + packing ----------------
// one thread = one 16B packed chunk per array (8 consecutive k of one row)
__global__ __launch_bounds__(256) void conv_pack(
    const float* __restrict__ triM, const float* __restrict__ d1w,
    const float* __restrict__ d2w, unsigned short* __restrict__ Mb,
    unsigned short* __restrict__ W1b, unsigned short* __restrict__ W2b) {
  const int cid = blockIdx.x * 256 + threadIdx.x;   // 0..32767
  const int i = cid >> 6, g = cid & 63;
  const int jb = g * 8;
  const size_t src = (size_t)i * 512 + jb;
  const size_t dst = ((size_t)((i >> 4) * 16 + (g >> 2)) * 64 + (g & 3) * 16 + (i & 15)) * 8;
  alignas(16) unsigned short o[8];
#pragma unroll
  for (int jj = 0; jj < 8; ++jj) o[jj] = (jb + jj <= i) ? f2bf(triM[src + jj]) : (unsigned short)0;
  *(uint4*)&Mb[dst] = *(const uint4*)o;
#pragma unroll
  for (int jj = 0; jj < 8; ++jj) o[jj] = f2bf(d1w[src + jj]);
  *(uint4*)&W1b[dst] = *(const uint4*)o;
#pragma unroll
  for (int jj = 0; jj < 8; ++jj) o[jj] = f2bf(d2w[src + jj]);
  *(uint4*)&W2b[dst] = *(const uint4*)o;
}

// ---------------- ln1 stats: per-batch sum / sumsq ----------------
__global__ __launch_bounds__(256) void ln_stats(const float* __restrict__ x,
                                                float* __restrict__ red) {
  const int b = blockIdx.x;
  const int s = blockIdx.y;                       // 16 splits
  const float4* p = (const float4*)(x + (size_t)b * TC_) + (size_t)s * 4096;
  float s1 = 0.f, s2 = 0.f;
  for (int i = threadIdx.x; i < 4096; i += 256) {
    float4 v = p[i];
    s1 += v.x + v.y + v.z + v.w;
    s2 += v.x * v.x + v.y * v.y + v.z * v.z + v.w * v.w;
  }
#pragma unroll
  for (int o = 32; o; o >>= 1) { s1 += __shfl_down(s1, o, 64); s2 += __shfl_down(s2, o, 64); }
  __shared__ float sm[8];
  const int w = threadIdx.x >> 6, lane = threadIdx.x & 63;
  if (lane == 0) { sm[w * 2] = s1; sm[w * 2 + 1] = s2; }
  __syncthreads();
  if (threadIdx.x == 0) {
    float a = 0.f, c = 0.f;
    for (int i = 0; i < 4; ++i) { a += sm[2 * i]; c += sm[2 * i + 1]; }
    atomicAdd(&red[b * 2], a);
    atomicAdd(&red[b * 2 + 1], c);
  }
}

// ------------- ln1 normalize + transposed PACKED bf16 write -------------
// logical XnT[b][c][t]; packed as B-operand (rows = c, k = t)
__global__ __launch_bounds__(256) void ln1_norm_t(
    const float* __restrict__ x, const float* __restrict__ w,
    const float* __restrict__ bvec, const float* __restrict__ red1,
    unsigned short* __restrict__ XnTp) {
  __shared__ unsigned short tile[64][65];
  const int b = blockIdx.z;
  const int t0 = blockIdx.y * 64;
  const int c0 = blockIdx.x * 64;
  const float mu = red1[b * 2] * (1.f / TC_);
  const float rstd = rsqrtf(red1[b * 2 + 1] * (1.f / TC_) - mu * mu + 1e-5f);
  const int tid = threadIdx.x;
  const int r = tid >> 4;            // 0..15
  const int cg = (tid & 15) * 4;     // 0..60
#pragma unroll
  for (int rr = 0; rr < 4; ++rr) {
    const int t = t0 + rr * 16 + r;
    const float4 xv = *(const float4*)&x[((size_t)b * T_ + t) * C_ + c0 + cg];
    const float4 wv = *(const float4*)&w[(size_t)t * C_ + c0 + cg];
    const float4 bv = *(const float4*)&bvec[(size_t)t * C_ + c0 + cg];
    tile[rr * 16 + r][cg + 0] = f2bf((xv.x - mu) * rstd * wv.x + bv.x);
    tile[rr * 16 + r][cg + 1] = f2bf((xv.y - mu) * rstd * wv.y + bv.y);
    tile[rr * 16 + r][cg + 2] = f2bf((xv.z - mu) * rstd * wv.z + bv.z);
    tile[rr * 16 + r][cg + 3] = f2bf((xv.w - mu) * rstd * wv.w + bv.w);
  }
  __syncthreads();
  const int cl = tid >> 2;           // c_local 0..63
  const int tg = (tid & 3) * 16;     // t_local base: 0,16,32,48
  alignas(16) unsigned short tmp[16];
#pragma unroll
  for (int j = 0; j < 16; ++j) tmp[j] = tile[tg + j][cl];
  const int c = c0 + cl;
  const int tb = t0 + tg;                       // multiple of 16
  const size_t chunk0 = (size_t)((c >> 4) * 16 + (tb >> 5)) * 64 +
                        ((tb >> 3) & 3) * 16 + (c & 15);
  unsigned short* o = XnTp + (size_t)b * TC_;
  *(uint4*)&o[chunk0 * 8]        = *(const uint4*)&tmp[0];
  *(uint4*)&o[(chunk0 + 16) * 8] = *(const uint4*)&tmp[8];
}

// ---------------- packed direct-from-global GEMM mainloop ----------------
// Ab/Bb: packed base already offset to (i0+wr) / (n0+wc) r-group, + lane*8.
// r-group stride = 16 ktiles * 512 shorts = 8192 shorts; kt stride = 512.
__device__ __forceinline__ void gemm_direct_packed(
    const unsigned short* __restrict__ Ab, const unsigned short* __restrict__ Bb,
    int ktiles, f32x4 acc[4][4]) {
  const unsigned short* ap[4];
  const unsigned short* bp[4];
#pragma unroll
  for (int r = 0; r < 4; ++r) ap[r] = Ab + (size_t)r * 8192;
#pragma unroll
  for (int c = 0; c < 4; ++c) bp[c] = Bb + (size_t)c * 8192;
  bf16x8 a[2][4], b[2][4];
#pragma unroll
  for (int r = 0; r < 4; ++r) a[0][r] = *(const bf16x8*)(ap[r]);
#pragma unroll
  for (int c = 0; c < 4; ++c) b[0][c] = *(const bf16x8*)(bp[c]);
  for (int kt = 0; kt < ktiles; kt += 2) {
    const int k1 = ((kt + 1) & 15) * 512;      // in-bounds; tail values unused
    const int k2 = ((kt + 2) & 15) * 512;
#pragma unroll
    for (int r = 0; r < 4; ++r) a[1][r] = *(const bf16x8*)(ap[r] + k1);
#pragma unroll
    for (int c = 0; c < 4; ++c) b[1][c] = *(const bf16x8*)(bp[c] + k1);
#pragma unroll
    for (int r = 0; r < 4; ++r)
#pragma unroll
      for (int c = 0; c < 4; ++c)
        acc[r][c] = __builtin_amdgcn_mfma_f32_16x16x32_bf16(a[0][r], b[0][c], acc[r][c], 0, 0, 0);
#pragma unroll
    for (int r = 0; r < 4; ++r) a[0][r] = *(const bf16x8*)(ap[r] + k2);
#pragma unroll
    for (int c = 0; c < 4; ++c) b[0][c] = *(const bf16x8*)(bp[c] + k2);
#pragma unroll
    for (int r = 0; r < 4; ++r)
#pragma unroll
      for (int c = 0; c < 4; ++c)
        acc[r][c] = __builtin_amdgcn_mfma_f32_16x16x32_bf16(a[1][r], b[1][c], acc[r][c], 0, 0, 0);
  }
}

// ---------------- mixer GEMM: Z = tril(M)@Xn + tri_b + inputs ----------------
__global__ __launch_bounds__(256) void gemm_mixer(
    const unsigned short* __restrict__ Mb, const unsigned short* __restrict__ XnTp,
    const float* __restrict__ trib, const float* __restrict__ inp,
    unsigned short* __restrict__ Z, float* __restrict__ red2) {
  const int b = blockIdx.z;
  const int i0 = blockIdx.y * 128;
  const int c0 = blockIdx.x * 128;
  const int tid = threadIdx.x, lane = tid & 63, w = tid >> 6;
  const int wr = (w >> 1) * 64, wc = (w & 1) * 64, m16 = lane & 15, quad = lane >> 4;
  f32x4 acc[4][4];
#pragma unroll
  for (int r = 0; r < 4; ++r)
#pragma unroll
    for (int c = 0; c < 4; ++c) acc[r][c] = (f32x4){0.f, 0.f, 0.f, 0.f};
  gemm_direct_packed(Mb + (size_t)((i0 + wr) >> 4) * 8192 + lane * 8,
                     XnTp + (size_t)b * TC_ + (size_t)((c0 + wc) >> 4) * 8192 + lane * 8,
                     (i0 >> 5) + 4, acc);
  float s1 = 0.f, s2 = 0.f;
#pragma unroll
  for (int r = 0; r < 4; ++r) {
#pragma unroll
    for (int g = 0; g < 4; ++g) {
      const int i = i0 + wr + r * 16 + quad * 4 + g;
      const float tb = trib[i];
      const float* inrow = &inp[((size_t)b * T_ + i) * C_];
      unsigned short* zrow = &Z[((size_t)b * T_ + i) * C_];
#pragma unroll
      for (int c = 0; c < 4; ++c) {
        const int ch = c0 + wc + c * 16 + m16;
        const float v = acc[r][c][g] + tb + inrow[ch];
        zrow[ch] = f2bf(v);
        s1 += v; s2 += v * v;
      }
    }
  }
#pragma unroll
  for (int o = 32; o; o >>= 1) { s1 += __shfl_down(s1, o, 64); s2 += __shfl_down(s2, o, 64); }
  __shared__ float sm[8];
  if (lane == 0) { sm[w * 2] = s1; sm[w * 2 + 1] = s2; }
  __syncthreads();
  if (tid == 0) {
    float a = 0.f, c2 = 0.f;
    for (int i = 0; i < 4; ++i) { a += sm[2 * i]; c2 += sm[2 * i + 1]; }
    atomicAdd(&red2[b * 2], a);
    atomicAdd(&red2[b * 2 + 1], c2);
  }
}

// ---------------- ln2 normalize -> packed X2 ----------------
// one block = one 16-row r-group (full 16KB packed region), 2048 blocks
__global__ __launch_bounds__(256) void ln2_norm(
    const unsigned short* __restrict__ Z, const float* __restrict__ red2,
    const float* __restrict__ w, const float* __restrict__ bvec,
    unsigned short* __restrict__ X2p) {
  const int rg = blockIdx.x;                 // row group
  const int bb = rg >> 5;                    // batch
  const float mu = red2[bb * 2] * (1.f / TC_);
  const float rstd = rsqrtf(red2[bb * 2 + 1] * (1.f / TC_) - mu * mu + 1e-5f);
  const int tid = threadIdx.x;
  const int wv = tid >> 6, cg = tid & 63;    // channel group (8 ch)
#pragma unroll
  for (int it = 0; it < 4; ++it) {
    const int m = it * 4 + wv;               // row within group
    const int row = rg * 16 + m;
    const int trow = row & 511;
    uint4 zp = *(const uint4*)&Z[(size_t)row * C_ + cg * 8];
    const unsigned short* zs = (const unsigned short*)&zp;
    alignas(16) float wvv[8], bvv[8];
    *(float4*)&wvv[0] = *(const float4*)&w[(size_t)trow * C_ + cg * 8];
    *(float4*)&wvv[4] = *(const float4*)&w[(size_t)trow * C_ + cg * 8 + 4];
    *(float4*)&bvv[0] = *(const float4*)&bvec[(size_t)trow * C_ + cg * 8];
    *(float4*)&bvv[4] = *(const float4*)&bvec[(size_t)trow * C_ + cg * 8 + 4];
    alignas(16) unsigned short o[8];
#pragma unroll
    for (int j = 0; j < 8; ++j)
      o[j] = f2bf((bf2f(zs[j]) - mu) * rstd * wvv[j] + bvv[j]);
    const size_t chunk = (size_t)rg * 1024 + (size_t)(cg >> 2) * 64 + (cg & 3) * 16 + m;
    *(uint4*)&X2p[chunk * 8] = *(const uint4*)o;
  }
}

// ---------------- MLP GEMM 1: H = gelu(X2 @ W1^T + b1), H packed ----------------
__global__ __launch_bounds__(256) void gemm_d1(
    const unsigned short* __restrict__ X2p, const unsigned short* __restrict__ W1p,
    const float* __restrict__ d1b, unsigned short* __restrict__ Hp) {
  const int i0 = blockIdx.y * 128;
  const int n0 = blockIdx.x * 128;
  const int tid = threadIdx.x, lane = tid & 63, w = tid >> 6;
  const int wr = (w >> 1) * 64, wc = (w & 1) * 64, m16 = lane & 15, quad = lane >> 4;
  f32x4 acc[4][4];
#pragma unroll
  for (int r = 0; r < 4; ++r)
#pragma unroll
    for (int c = 0; c < 4; ++c) acc[r][c] = (f32x4){0.f, 0.f, 0.f, 0.f};
  gemm_direct_packed(X2p + (size_t)((i0 + wr) >> 4) * 8192 + lane * 8,
                     W1p + (size_t)((n0 + wc) >> 4) * 8192 + lane * 8, 16, acc);
#pragma unroll
  for (int r = 0; r < 4; ++r) {
#pragma unroll
    for (int g = 0; g < 4; ++g) {
      const int row = i0 + wr + r * 16 + quad * 4 + g;
#pragma unroll
      for (int c = 0; c < 4; ++c) {
        const int n = n0 + wc + c * 16 + m16;
        const float v = acc[r][c][g] + d1b[n];
        const float gl = 0.5f * v * (1.0f + erff(v * 0.70710678118654752f));
        Hp[pidx(row, n)] = f2bf(gl);
      }
    }
  }
}

// ---------------- MLP GEMM 2: out = X2 + H @ W2^T + b2 ----------------
__global__ __launch_bounds__(256) void gemm_d2(
    const unsigned short* __restrict__ Hp, const unsigned short* __restrict__ W2p,
    const float* __restrict__ d2b, const unsigned short* __restrict__ X2p,
    float* __restrict__ out) {
  const int i0 = blockIdx.y * 128;
  const int n0 = blockIdx.x * 128;
  const int tid = threadIdx.x, lane = tid & 63, w = tid >> 6;
  const int wr = (w >> 1) * 64, wc = (w & 1) * 64, m16 = lane & 15, quad = lane >> 4;
  f32x4 acc[4][4];
#pragma unroll
  for (int r = 0; r < 4; ++r)
#pragma unroll
    for (int c = 0; c < 4; ++c) acc[r][c] = (f32x4){0.f, 0.f, 0.f, 0.f};
  gemm_direct_packed(Hp + (size_t)((i0 + wr) >> 4) * 8192 + lane * 8,
                     W2p + (size_t)((n0 + wc) >> 4) * 8192 + lane * 8, 16, acc);
#pragma unroll
  for (int r = 0; r < 4; ++r) {
#pragma unroll
    for (int g = 0; g < 4; ++g) {
      const int row = i0 + wr + r * 16 + quad * 4 + g;
#pragma unroll
      for (int c = 0; c < 4; ++c) {
        const int n = n0 + wc + c * 16 + m16;
        out[(size_t)row * C_ + n] = acc[r][c][g] + d2b[n] + bf2f(X2p[pidx(row, n)]);
      }
    }
  }
}

extern "C" void kernel_launch(void* const* d_in, const int* in_sizes, int n_in,
                              void* d_out, int out_size, void* d_ws, size_t ws_size,
                              hipStream_t stream) {
  const float* inp  = (const float*)d_in[0];
  const float* ln1w = (const float*)d_in[1];
  const float* ln1b = (const float*)d_in[2];
  const float* ln2w = (const float*)d_in[3];
  const float* ln2b = (const float*)d_in[4];
  const float* triM = (const float*)d_in[5];
  const float* trib = (const float*)d_in[6];
  const float* d1w  = (const float*)d_in[7];
  const float* d1b  = (const float*)d_in[8];
  const float* d2w  = (const float*)d_in[9];
  const float* d2b  = (const float*)d_in[10];
  float* out = (float*)d_out;

  char* ws = (char*)d_ws;
  float* red1 = (float*)ws;                         // 64*2 floats
  float* red2 = (float*)(ws + 512);                 // 64*2 floats
  unsigned short* Mb  = (unsigned short*)(ws + 1024);
  unsigned short* W1b = Mb + TC_;
  unsigned short* W2b = W1b + TC_;
  unsigned short* XnT = W2b + TC_;                  // [B] packed (rows=c, k=t)
  unsigned short* Z   = XnT + (size_t)B_ * TC_;     // [B][T][C] row-major bf16
  unsigned short* X2  = Z + (size_t)B_ * TC_;       // packed (rows, k=c)
  unsigned short* H   = X2 + (size_t)B_ * TC_;      // packed (rows, k=h)

  hipMemsetAsync(ws, 0, 1024, stream);
  conv_pack<<<128, 256, 0, stream>>>(triM, d1w, d2w, Mb, W1b, W2b);
  ln_stats<<<dim3(B_, 16), 256, 0, stream>>>(inp, red1);
  ln1_norm_t<<<dim3(8, 8, B_), 256, 0, stream>>>(inp, ln1w, ln1b, red1, XnT);
  gemm_mixer<<<dim3(4, 4, B_), 256, 0, stream>>>(Mb, XnT, trib, inp, Z, red2);
  ln2_norm<<<2048, 256, 0, stream>>>(Z, red2, ln2w, ln2b, X2);
  gemm_d1<<<dim3(4, 256), 256, 0, stream>>>(X2, W1b, d1b, H);
  gemm_d2<<<dim3(4, 256), 256, 0, stream>>>(H, W2b, d2b, X2, out);
}